// Round 6
// baseline (479.080 us; speedup 1.0000x reference)
//
#include <hip/hip_runtime.h>
#include <math.h>

// ============================================================================
// ROUND 6: ATTRIBUTION EXPERIMENT. Pipeline is launched TWICE (idempotent,
// deterministic -- second pass rewrites identical values). dur_us delta vs
// round 5 (383.2) == exact total kernel time T(k1)+T(k2)+T(k3), resolving
// "kernels ~50us + big harness floor" vs "kernels ~137us (k1 off-model)".
// Kernel code itself is identical to round 5.
// ============================================================================

// Problem constants (B,S,H,D,P fixed by the reference).
#define B_ 16
#define S_ 512
#define H_ 12
#define D_ 768
#define P_ 256
#define K_ 51
#define CH_ 16            // s-rows per k2 chunk
#define NCHUNK_ (S_/CH_)  // 32

// Monotonic float->uint key: larger float <=> larger unsigned.
__device__ __forceinline__ unsigned okey(float f) {
  unsigned u = __float_as_uint(f);
  return (u & 0x80000000u) ? ~u : (u | 0x80000000u);
}

// k1: one WAVE per (b,t) attention row. Head-average (coalesced float4
// streaming), exact top-K select via branchless fixed-trip radix bisection on
// ballots. Emits per-row selection bitmask + invcnt.
__global__ __launch_bounds__(256, 8) void k1_topk_mask(
    const float* __restrict__ attn, unsigned long long* __restrict__ maskbuf,
    float* __restrict__ invbuf) {
  const int tid = threadIdx.x;
  const int wv = tid >> 6;
  const int lane = tid & 63;
  const int bt = blockIdx.x * 4 + wv;
  const int b = bt >> 9;            // S_ == 512
  const int t = bt & (S_ - 1);

  // --- head-average: lane owns columns {4*lane+i, 256+4*lane+i} ---
  const float* base = attn + (((size_t)b * H_) * S_ + t) * S_;
  float a[8] = {0.f, 0.f, 0.f, 0.f, 0.f, 0.f, 0.f, 0.f};
  #pragma unroll
  for (int h = 0; h < H_; ++h) {
    const float* r = base + (size_t)h * (S_ * S_);
    const float4 u = *(const float4*)(r + 4 * lane);
    const float4 v = *(const float4*)(r + 256 + 4 * lane);
    a[0] += u.x; a[1] += u.y; a[2] += u.z; a[3] += u.w;
    a[4] += v.x; a[5] += v.y; a[6] += v.z; a[7] += v.w;
  }
  unsigned k[8];
  #pragma unroll
  for (int i = 0; i < 8; ++i) {
    a[i] *= (1.0f / (float)H_);
    k[i] = okey(a[i]);
  }

  // --- row-wide positive count via ballots (wave-uniform result) ---
  int p = 0;
  #pragma unroll
  for (int i = 0; i < 8; ++i) p += __popcll(__ballot(a[i] > 0.f));

  bool sel[8];
  float invcnt;
  if (p >= 1 && p < K_) {
    #pragma unroll
    for (int i = 0; i < 8; ++i) sel[i] = (a[i] > 0.f);
    invcnt = 1.0f / (float)p;
  } else {
    // Branchless exact top-K radix bisection, fixed 32 trips.
    unsigned prefix = 0;
    unsigned rem = K_;
    #pragma unroll
    for (int bpos = 31; bpos >= 0; --bpos) {
      const unsigned cand = prefix | (1u << bpos);
      const unsigned ch = cand >> bpos;        // wave-uniform scalar
      unsigned cnt = 0;
      #pragma unroll
      for (int i = 0; i < 8; ++i)
        cnt += (unsigned)__popcll(__ballot((k[i] >> bpos) == ch));
      const bool ge = (cnt >= rem);
      prefix = ge ? cand : prefix;
      rem = ge ? rem : (rem - cnt);
    }
    const unsigned T = prefix;
    // Keep all k > T, plus the `rem` lowest-column-index keys equal to T.
    unsigned long long mm[8];
    #pragma unroll
    for (int i = 0; i < 8; ++i) mm[i] = __ballot(k[i] == T);
    const unsigned long long lt = ((unsigned long long)1 << lane) - 1ull;
    int fh = 0;
    #pragma unroll
    for (int i = 0; i < 4; ++i) fh += __popcll(mm[i]);
    #pragma unroll
    for (int i = 0; i < 8; ++i) {
      sel[i] = (k[i] > T);
      if (k[i] == T) {
        int r = 0;
        if (i < 4) {
          #pragma unroll
          for (int i2 = 0; i2 < 4; ++i2) r += __popcll(mm[i2] & lt);
          for (int i2 = 0; i2 < i; ++i2) r += (int)((mm[i2] >> lane) & 1ull);
        } else {
          r = fh;
          #pragma unroll
          for (int i2 = 4; i2 < 8; ++i2) r += __popcll(mm[i2] & lt);
          for (int i2 = 4; i2 < i; ++i2) r += (int)((mm[i2] >> lane) & 1ull);
        }
        if (r < (int)rem) sel[i] = true;
      }
    }
    invcnt = 1.0f / (float)K_;
  }

  // --- emit selection bitmask + invcnt (plain stores, no atomics) ---
  unsigned long long m[8];
  #pragma unroll
  for (int i = 0; i < 8; ++i) m[i] = __ballot(sel[i]);
  if (lane == 0) {
    ulonglong2* mp = (ulonglong2*)(maskbuf + (size_t)bt * 8);
    mp[0] = ulonglong2{m[0], m[1]};
    mp[1] = ulonglong2{m[2], m[3]};
    mp[2] = ulonglong2{m[4], m[5]};
    mp[3] = ulonglong2{m[6], m[7]};
    invbuf[bt] = invcnt;
  }
}

// k2: fused colsum + weighted partial sum (unchanged from round 5).
__global__ __launch_bounds__(192) void k2_colsum_wsum(
    const unsigned long long* __restrict__ maskbuf,
    const float* __restrict__ invbuf, const float* __restrict__ node_eta,
    const float* __restrict__ hidden, float* __restrict__ x_part) {
  const int chunk = blockIdx.x;
  const int b = blockIdx.y;
  const int tid = threadIdx.x;
  __shared__ unsigned long long ld[S_ * 4];  // 16 KB: words wi0..wi0+3 per t
  __shared__ float inv[S_];                  // 2 KB
  __shared__ float part[16][8];
  __shared__ float cs[CH_];

  const int wi0 = (chunk < 16) ? 0 : 4;
  for (int i = tid; i < S_ * 4; i += 192) {
    const int t = i >> 2, j = i & 3;
    ld[i] = maskbuf[(((size_t)b << 9) + t) * 8 + wi0 + j];
  }
  for (int i = tid; i < S_; i += 192) inv[i] = invbuf[(b << 9) + i];
  __syncthreads();

  if (tid < 128) {
    const int c = tid >> 3, g = tid & 7;     // 16 cols x 8 t-groups
    const int s = chunk * CH_ + c;
    const int j = s & 3;
    const unsigned long long bm = 1ull << ((s & 255) >> 2);
    float w = 0.f;
    #pragma unroll 8
    for (int i = 0; i < 64; ++i) {
      const int t = i * 8 + g;               // interleaved: 2-way LDS max
      if (ld[t * 4 + j] & bm) w += inv[t];
    }
    part[c][g] = w;
  }
  __syncthreads();
  if (tid < CH_) {
    float w = 0.f;
    #pragma unroll
    for (int g = 0; g < 8; ++g) w += part[tid][g];
    const float eta = node_eta[0];
    cs[tid] = (eta + (1.0f - eta) * w) * (1.0f / (float)S_);
  }
  __syncthreads();

  const float* hb = hidden + ((size_t)b * S_ + (size_t)chunk * CH_) * D_ + 4 * tid;
  float4 acc = make_float4(0.f, 0.f, 0.f, 0.f);
  #pragma unroll
  for (int s = 0; s < CH_; ++s) {
    const float4 v = *(const float4*)(hb + (size_t)s * D_);
    const float c = cs[s];
    acc.x += c * v.x; acc.y += c * v.y; acc.z += c * v.z; acc.w += c * v.w;
  }
  *(float4*)(x_part + ((size_t)chunk * B_ + b) * D_ + 4 * tid) = acc;
}

// k3: full tail per batch row (unchanged from round 5).
__global__ __launch_bounds__(256) void k3_tail(
    const float* __restrict__ x_part, const float* __restrict__ W_node,
    const float* __restrict__ b_node, const float* __restrict__ W_fc,
    const float* __restrict__ b_fc, const float* __restrict__ gamma,
    const float* __restrict__ beta, float* __restrict__ out) {
  const int b = blockIdx.x;
  const int tid = threadIdx.x;
  __shared__ float xs[D_];
  __shared__ float ts[P_];
  __shared__ float red[4];

  #pragma unroll
  for (int d = tid; d < D_; d += 256) {
    float s = 0.f;
    #pragma unroll 8
    for (int c = 0; c < NCHUNK_; ++c)
      s += x_part[((size_t)c * B_ + b) * D_ + d];
    xs[d] = s;
  }
  __syncthreads();

  float acc = 0.f;
  #pragma unroll 8
  for (int d = 0; d < D_; ++d) acc += xs[d] * W_node[(size_t)d * P_ + tid];
  ts[tid] = tanhf(acc + b_node[tid]);
  __syncthreads();

  float o = 0.f;
  #pragma unroll 8
  for (int q = 0; q < P_; ++q) o += ts[q] * W_fc[(size_t)q * P_ + tid];
  o += b_fc[tid];

  float s = o;
  #pragma unroll
  for (int off = 32; off > 0; off >>= 1) s += __shfl_down(s, off, 64);
  const int wave = tid >> 6, lane = tid & 63;
  if (lane == 0) red[wave] = s;
  __syncthreads();
  const float mu = (red[0] + red[1] + red[2] + red[3]) * (1.0f / (float)P_);
  __syncthreads();
  const float dv = o - mu;
  float s2 = dv * dv;
  #pragma unroll
  for (int off = 32; off > 0; off >>= 1) s2 += __shfl_down(s2, off, 64);
  if (lane == 0) red[wave] = s2;
  __syncthreads();
  const float var = (red[0] + red[1] + red[2] + red[3]) * (1.0f / (float)P_);
  const float inv = 1.0f / sqrtf(var + 1e-5f);
  out[b * P_ + tid] = dv * inv * gamma[tid] + beta[tid];
}

extern "C" void kernel_launch(void* const* d_in, const int* in_sizes, int n_in,
                              void* d_out, int out_size, void* d_ws, size_t ws_size,
                              hipStream_t stream) {
  (void)in_sizes; (void)n_in; (void)out_size; (void)ws_size;
  const float* hidden   = (const float*)d_in[0];  // [B,S,D]
  const float* attn     = (const float*)d_in[1];  // [B,H,S,S]
  /* d_in[2] = length (== S, unused) */
  const float* W_node   = (const float*)d_in[3];  // [D,P]
  const float* b_node   = (const float*)d_in[4];  // [P]
  const float* node_eta = (const float*)d_in[5];  // [1]
  const float* W_fc     = (const float*)d_in[6];  // [P,P]
  const float* b_fc     = (const float*)d_in[7];  // [P]
  const float* gamma    = (const float*)d_in[8];  // [P]
  const float* beta     = (const float*)d_in[9];  // [P]
  float* out = (float*)d_out;                     // [B,P] fp32

  // Workspace layout (16B-aligned pieces, ~2.1 MB total). No memsets needed:
  // every workspace word is written before it is read.
  unsigned long long* maskbuf = (unsigned long long*)d_ws;   // B*S*8 u64 (512 KB)
  float* invbuf = (float*)(maskbuf + (size_t)B_ * S_ * 8);   // B*S (32 KB)
  float* x_part = invbuf + B_ * S_;                          // NCHUNK*B*D (1.5 MB)

  // ATTRIBUTION: run the full pipeline TWICE. Second pass recomputes and
  // rewrites identical values (pure functions of the inputs), so the output
  // is unchanged; dur_us delta vs round 5 == exact total kernel time.
  #pragma unroll
  for (int rep = 0; rep < 2; ++rep) {
    k1_topk_mask<<<(B_ * S_) / 4, 256, 0, stream>>>(attn, maskbuf, invbuf);
    k2_colsum_wsum<<<dim3(NCHUNK_, B_), 192, 0, stream>>>(maskbuf, invbuf,
                                                          node_eta, hidden,
                                                          x_part);
    k3_tail<<<B_, 256, 0, stream>>>(x_part, W_node, b_node, W_fc, b_fc,
                                    gamma, beta, out);
  }
}

// Round 7
// 331.182 us; speedup vs baseline: 1.4466x; 1.4466x over previous
//
#include <hip/hip_runtime.h>
#include <math.h>

// Problem constants (B,S,H,D,P fixed by the reference).
#define B_ 16
#define S_ 512
#define H_ 12
#define D_ 768
#define P_ 256
#define K_ 51
#define CH_ 16            // s-rows per k2 chunk
#define NCHUNK_ (S_/CH_)  // 32

// Monotonic float->uint key: larger float <=> larger unsigned.
__device__ __forceinline__ unsigned okey(float f) {
  unsigned u = __float_as_uint(f);
  return (u & 0x80000000u) ? ~u : (u | 0x80000000u);
}

// k1: one WAVE per (b,t) attention row. Head-average (coalesced float4
// streaming, BW-bound ~30us for 201 MB), exact top-K select via branchless
// fixed-trip radix bisection on ballots (fully hidden under the memory
// shadow). Emits per-row selection bitmask + invcnt.
__global__ __launch_bounds__(256, 8) void k1_topk_mask(
    const float* __restrict__ attn, unsigned long long* __restrict__ maskbuf,
    float* __restrict__ invbuf) {
  const int tid = threadIdx.x;
  const int wv = tid >> 6;
  const int lane = tid & 63;
  const int bt = blockIdx.x * 4 + wv;
  const int b = bt >> 9;            // S_ == 512
  const int t = bt & (S_ - 1);

  // --- head-average: lane owns columns {4*lane+i, 256+4*lane+i} ---
  const float* base = attn + (((size_t)b * H_) * S_ + t) * S_;
  float a[8] = {0.f, 0.f, 0.f, 0.f, 0.f, 0.f, 0.f, 0.f};
  #pragma unroll
  for (int h = 0; h < H_; ++h) {
    const float* r = base + (size_t)h * (S_ * S_);
    const float4 u = *(const float4*)(r + 4 * lane);
    const float4 v = *(const float4*)(r + 256 + 4 * lane);
    a[0] += u.x; a[1] += u.y; a[2] += u.z; a[3] += u.w;
    a[4] += v.x; a[5] += v.y; a[6] += v.z; a[7] += v.w;
  }
  unsigned k[8];
  #pragma unroll
  for (int i = 0; i < 8; ++i) {
    a[i] *= (1.0f / (float)H_);
    k[i] = okey(a[i]);
  }

  // --- row-wide positive count via ballots (wave-uniform result) ---
  int p = 0;
  #pragma unroll
  for (int i = 0; i < 8; ++i) p += __popcll(__ballot(a[i] > 0.f));

  bool sel[8];
  float invcnt;
  if (p >= 1 && p < K_) {
    #pragma unroll
    for (int i = 0; i < 8; ++i) sel[i] = (a[i] > 0.f);
    invcnt = 1.0f / (float)p;
  } else {
    // Branchless exact top-K radix bisection, fixed 32 trips.
    unsigned prefix = 0;
    unsigned rem = K_;
    #pragma unroll
    for (int bpos = 31; bpos >= 0; --bpos) {
      const unsigned cand = prefix | (1u << bpos);
      const unsigned ch = cand >> bpos;        // wave-uniform scalar
      unsigned cnt = 0;
      #pragma unroll
      for (int i = 0; i < 8; ++i)
        cnt += (unsigned)__popcll(__ballot((k[i] >> bpos) == ch));
      const bool ge = (cnt >= rem);
      prefix = ge ? cand : prefix;
      rem = ge ? rem : (rem - cnt);
    }
    const unsigned T = prefix;
    // Keep all k > T, plus the `rem` lowest-column-index keys equal to T.
    unsigned long long mm[8];
    #pragma unroll
    for (int i = 0; i < 8; ++i) mm[i] = __ballot(k[i] == T);
    const unsigned long long lt = ((unsigned long long)1 << lane) - 1ull;
    int fh = 0;
    #pragma unroll
    for (int i = 0; i < 4; ++i) fh += __popcll(mm[i]);
    #pragma unroll
    for (int i = 0; i < 8; ++i) {
      sel[i] = (k[i] > T);
      if (k[i] == T) {
        int r = 0;
        if (i < 4) {
          #pragma unroll
          for (int i2 = 0; i2 < 4; ++i2) r += __popcll(mm[i2] & lt);
          for (int i2 = 0; i2 < i; ++i2) r += (int)((mm[i2] >> lane) & 1ull);
        } else {
          r = fh;
          #pragma unroll
          for (int i2 = 4; i2 < 8; ++i2) r += __popcll(mm[i2] & lt);
          for (int i2 = 4; i2 < i; ++i2) r += (int)((mm[i2] >> lane) & 1ull);
        }
        if (r < (int)rem) sel[i] = true;
      }
    }
    invcnt = 1.0f / (float)K_;
  }

  // --- emit selection bitmask + invcnt (plain stores, no atomics) ---
  unsigned long long m[8];
  #pragma unroll
  for (int i = 0; i < 8; ++i) m[i] = __ballot(sel[i]);
  if (lane == 0) {
    ulonglong2* mp = (ulonglong2*)(maskbuf + (size_t)bt * 8);
    mp[0] = ulonglong2{m[0], m[1]};
    mp[1] = ulonglong2{m[2], m[3]};
    mp[2] = ulonglong2{m[4], m[5]};
    mp[3] = ulonglong2{m[6], m[7]};
    invbuf[bt] = invcnt;
  }
}

// k2: fused colsum + weighted partial sum (unchanged, proven).
__global__ __launch_bounds__(192) void k2_colsum_wsum(
    const unsigned long long* __restrict__ maskbuf,
    const float* __restrict__ invbuf, const float* __restrict__ node_eta,
    const float* __restrict__ hidden, float* __restrict__ x_part) {
  const int chunk = blockIdx.x;
  const int b = blockIdx.y;
  const int tid = threadIdx.x;
  __shared__ unsigned long long ld[S_ * 4];  // 16 KB: words wi0..wi0+3 per t
  __shared__ float inv[S_];                  // 2 KB
  __shared__ float part[16][8];
  __shared__ float cs[CH_];

  const int wi0 = (chunk < 16) ? 0 : 4;
  for (int i = tid; i < S_ * 4; i += 192) {
    const int t = i >> 2, j = i & 3;
    ld[i] = maskbuf[(((size_t)b << 9) + t) * 8 + wi0 + j];
  }
  for (int i = tid; i < S_; i += 192) inv[i] = invbuf[(b << 9) + i];
  __syncthreads();

  if (tid < 128) {
    const int c = tid >> 3, g = tid & 7;     // 16 cols x 8 t-groups
    const int s = chunk * CH_ + c;
    const int j = s & 3;
    const unsigned long long bm = 1ull << ((s & 255) >> 2);
    float w = 0.f;
    #pragma unroll 8
    for (int i = 0; i < 64; ++i) {
      const int t = i * 8 + g;               // interleaved: 2-way LDS max
      if (ld[t * 4 + j] & bm) w += inv[t];
    }
    part[c][g] = w;
  }
  __syncthreads();
  if (tid < CH_) {
    float w = 0.f;
    #pragma unroll
    for (int g = 0; g < 8; ++g) w += part[tid][g];
    const float eta = node_eta[0];
    cs[tid] = (eta + (1.0f - eta) * w) * (1.0f / (float)S_);
  }
  __syncthreads();

  const float* hb = hidden + ((size_t)b * S_ + (size_t)chunk * CH_) * D_ + 4 * tid;
  float4 acc = make_float4(0.f, 0.f, 0.f, 0.f);
  #pragma unroll
  for (int s = 0; s < CH_; ++s) {
    const float4 v = *(const float4*)(hb + (size_t)s * D_);
    const float c = cs[s];
    acc.x += c * v.x; acc.y += c * v.y; acc.z += c * v.z; acc.w += c * v.w;
  }
  *(float4*)(x_part + ((size_t)chunk * B_ + b) * D_ + 4 * tid) = acc;
}

// k2b: deterministic reduction of the 32 chunk partials -> x[b,d].
// grid (3, B) x 256 threads: thread owns one d; 32 coalesced strided loads.
__global__ __launch_bounds__(256) void k2b_reduce(
    const float* __restrict__ x_part, float* __restrict__ x) {
  const int d = blockIdx.x * 256 + threadIdx.x;  // 0..767
  const int b = blockIdx.y;
  float s = 0.f;
  #pragma unroll 8
  for (int c = 0; c < NCHUNK_; ++c)
    s += x_part[((size_t)c * B_ + b) * D_ + d];
  x[b * D_ + d] = s;
}

// k3a: t[b,p] = tanh(x[b,:]@W_node[:,p] + b_node[p]) for a 32-col slice.
// grid (8, B) = 128 blocks, block 256 = 16 float2-cols x 16 d-groups of 48.
// (R0-proven tail structure: short 48-iter loops, wide block parallelism --
// the R2 "fused" tail ran on 16 blocks with 768-iter serial loops and cost
// ~45us of pure load latency.)
__global__ __launch_bounds__(256) void k3a_tanh_matvec(
    const float* __restrict__ x, const float* __restrict__ W_node,
    const float* __restrict__ b_node, float* __restrict__ tbuf) {
  const int j = blockIdx.x;   // 32-column slice
  const int b = blockIdx.y;
  const int tid = threadIdx.x;
  const int pp = tid & 15;    // float2 column pair
  const int g = tid >> 4;     // d-group
  __shared__ float xs[D_];
  __shared__ float part[16][32];
  for (int d = tid; d < D_; d += 256) xs[d] = x[b * D_ + d];
  __syncthreads();
  const float* Wp = W_node + 32 * j + 2 * pp;
  float2 acc = make_float2(0.f, 0.f);
  const int d0 = 48 * g;
  #pragma unroll 8
  for (int dd = 0; dd < 48; ++dd) {
    const int d = d0 + dd;
    const float2 wv = *(const float2*)(Wp + (size_t)d * P_);
    const float xv = xs[d];
    acc.x += xv * wv.x; acc.y += xv * wv.y;
  }
  *(float2*)&part[g][2 * pp] = acc;
  __syncthreads();
  if (tid < 32) {
    float s = 0.f;
    #pragma unroll
    for (int gg = 0; gg < 16; ++gg) s += part[gg][tid];
    const int pcol = 32 * j + tid;
    tbuf[b * P_ + pcol] = tanhf(s + b_node[pcol]);
  }
}

// k3b: o[b,p] = t[b,:]@W_fc[:,p] + b_fc[p] for a 64-col slice.
// grid (4, B) = 64 blocks, block 256 = 32 float2-cols x 8 q-groups of 32.
__global__ __launch_bounds__(256) void k3b_fc(
    const float* __restrict__ tbuf, const float* __restrict__ W_fc,
    const float* __restrict__ b_fc, float* __restrict__ obuf) {
  const int j = blockIdx.x;
  const int b = blockIdx.y;
  const int tid = threadIdx.x;
  const int pp = tid & 31;
  const int g = tid >> 5;
  __shared__ float ts[P_];
  __shared__ float part[8][64];
  ts[tid] = tbuf[b * P_ + tid];
  __syncthreads();
  const float* Wp = W_fc + 64 * j + 2 * pp;
  float2 acc = make_float2(0.f, 0.f);
  const int q0 = 32 * g;
  #pragma unroll 8
  for (int qq = 0; qq < 32; ++qq) {
    const int q = q0 + qq;
    const float2 wv = *(const float2*)(Wp + (size_t)q * P_);
    const float tv = ts[q];
    acc.x += tv * wv.x; acc.y += tv * wv.y;
  }
  *(float2*)&part[g][2 * pp] = acc;
  __syncthreads();
  if (tid < 64) {
    float s = 0.f;
    #pragma unroll
    for (int gg = 0; gg < 8; ++gg) s += part[gg][tid];
    const int pcol = 64 * j + tid;
    obuf[b * P_ + pcol] = s + b_fc[pcol];
  }
}

// k3c: LayerNorm over P per batch row.
__global__ __launch_bounds__(256) void k3c_layernorm(
    const float* __restrict__ obuf, const float* __restrict__ gamma,
    const float* __restrict__ beta, float* __restrict__ out) {
  const int b = blockIdx.x;
  const int tid = threadIdx.x;
  __shared__ float red[4];
  const float o = obuf[b * P_ + tid];
  float s = o;
  #pragma unroll
  for (int off = 32; off > 0; off >>= 1) s += __shfl_down(s, off, 64);
  const int wave = tid >> 6, lane = tid & 63;
  if (lane == 0) red[wave] = s;
  __syncthreads();
  const float mu = (red[0] + red[1] + red[2] + red[3]) * (1.0f / (float)P_);
  __syncthreads();
  const float dv = o - mu;
  float s2 = dv * dv;
  #pragma unroll
  for (int off = 32; off > 0; off >>= 1) s2 += __shfl_down(s2, off, 64);
  if (lane == 0) red[wave] = s2;
  __syncthreads();
  const float var = (red[0] + red[1] + red[2] + red[3]) * (1.0f / (float)P_);
  const float inv = 1.0f / sqrtf(var + 1e-5f);
  out[b * P_ + tid] = dv * inv * gamma[tid] + beta[tid];
}

extern "C" void kernel_launch(void* const* d_in, const int* in_sizes, int n_in,
                              void* d_out, int out_size, void* d_ws, size_t ws_size,
                              hipStream_t stream) {
  (void)in_sizes; (void)n_in; (void)out_size; (void)ws_size;
  const float* hidden   = (const float*)d_in[0];  // [B,S,D]
  const float* attn     = (const float*)d_in[1];  // [B,H,S,S]
  /* d_in[2] = length (== S, unused) */
  const float* W_node   = (const float*)d_in[3];  // [D,P]
  const float* b_node   = (const float*)d_in[4];  // [P]
  const float* node_eta = (const float*)d_in[5];  // [1]
  const float* W_fc     = (const float*)d_in[6];  // [P,P]
  const float* b_fc     = (const float*)d_in[7];  // [P]
  const float* gamma    = (const float*)d_in[8];  // [P]
  const float* beta     = (const float*)d_in[9];  // [P]
  float* out = (float*)d_out;                     // [B,P] fp32

  // Workspace layout (16B-aligned pieces, ~2.2 MB total). No memsets needed:
  // every workspace word is written before it is read.
  unsigned long long* maskbuf = (unsigned long long*)d_ws;   // B*S*8 u64 (512 KB)
  float* invbuf = (float*)(maskbuf + (size_t)B_ * S_ * 8);   // B*S (32 KB)
  float* x_part = invbuf + B_ * S_;                          // NCHUNK*B*D (1.5 MB)
  float* x      = x_part + (size_t)NCHUNK_ * B_ * D_;        // B*D (48 KB)
  float* tbuf   = x + B_ * D_;                               // B*P (16 KB)
  float* obuf   = tbuf + B_ * P_;                            // B*P (16 KB)

  k1_topk_mask<<<(B_ * S_) / 4, 256, 0, stream>>>(attn, maskbuf, invbuf);
  k2_colsum_wsum<<<dim3(NCHUNK_, B_), 192, 0, stream>>>(maskbuf, invbuf,
                                                        node_eta, hidden, x_part);
  k2b_reduce<<<dim3(3, B_), 256, 0, stream>>>(x_part, x);
  k3a_tanh_matvec<<<dim3(8, B_), 256, 0, stream>>>(x, W_node, b_node, tbuf);
  k3b_fc<<<dim3(4, B_), 256, 0, stream>>>(tbuf, W_fc, b_fc, obuf);
  k3c_layernorm<<<B_, 256, 0, stream>>>(obuf, gamma, beta, out);
}